// Round 7
// baseline (266.951 us; speedup 1.0000x reference)
//
#include <hip/hip_runtime.h>

#define N_PTS 4096
#define ICP_STEPS 10
#define NBLK 256          // 1 block/CU (cooperative launch guarantees co-residency)
#define BS 256            // 4 waves/block; 4 queries per wave -> 16 queries/block
#define NWAVE (BS / 64)
#define QPW 4
#define POWER_ITERS 16
#define RSLOT 18          // 15 data + cs1 + cs2 + count
#define FP_SCALE 16777216.0   // 2^24 fixed point
#define FP_INV   (1.0 / 16777216.0)

// rows: [ICP_STEPS][NBLK][RSLOT] u64 in d_ws. No zeroing needed: a row is
// accepted only if count==1 AND both checksums match; 0xAA poison or a
// partially-landed row fails verification.

__device__ __forceinline__ void ast64(unsigned long long* p, unsigned long long v) {
    __hip_atomic_store(p, v, __ATOMIC_RELAXED, __HIP_MEMORY_SCOPE_AGENT);
}
__device__ __forceinline__ unsigned long long ald64(const unsigned long long* p) {
    return __hip_atomic_load(p, __ATOMIC_RELAXED, __HIP_MEMORY_SCOPE_AGENT);
}

__global__ __launch_bounds__(BS, 1) void icp_pk(const float* __restrict__ p1,
                                                const float* __restrict__ p2,
                                                unsigned long long* __restrict__ rows,
                                                float* __restrict__ out) {
    __shared__ __align__(16) float4 sp2[N_PTS];   // 64 KB {x,y,z,|p|^2}
    __shared__ float wred[NWAVE][16];
    __shared__ long long sred[RSLOT];
    __shared__ long long lred[NWAVE][15];
    __shared__ float sH[16];

    const int tid = threadIdx.x;
    const int bid = blockIdx.x;
    const int wave = tid >> 6;
    const int lane = tid & 63;

    // ---- stage p2 -> LDS once ----
    for (int p = tid; p < N_PTS; p += BS) {
        const float x = p2[3 * p + 0];
        const float y = p2[3 * p + 1];
        const float z = p2[3 * p + 2];
        sp2[p] = make_float4(x, y, z, x * x + y * y + z * z);
    }

    // ---- owned queries: 16/block, 4/wave (all lanes track the same 4) ----
    const int qb = bid * 16 + wave * QPW;
    float qx[QPW], qy[QPW], qz[QPW];
    #pragma unroll
    for (int j = 0; j < QPW; ++j) {
        qx[j] = p1[3 * (qb + j) + 0];
        qy[j] = p1[3 * (qb + j) + 1];
        qz[j] = p1[3 * (qb + j) + 2];
    }

    // composed transform (tracked identically by all blocks; bid0 writes out)
    float cqw = 1.0f, cqx = 0.0f, cqy = 0.0f, cqz = 0.0f;
    float ctx = 0.0f, cty = 0.0f, ctz = 0.0f;

    __syncthreads();

    for (int s = 0; s < ICP_STEPS; ++s) {
        // ---- 1-NN for 4 queries: argmin_j (|p_j|^2 - 2 q.p_j) ----
        float ax[QPW], ay[QPW], az[QPW], best[QPW];
        int idx[QPW];
        #pragma unroll
        for (int j = 0; j < QPW; ++j) {
            ax[j] = -2.0f * qx[j]; ay[j] = -2.0f * qy[j]; az[j] = -2.0f * qz[j];
            best[j] = 3.4e38f; idx[j] = 0;
        }
        #pragma unroll 8
        for (int k = 0; k < N_PTS / 64; ++k) {
            const int j = lane + (k << 6);
            const float4 P = sp2[j];
            #pragma unroll
            for (int q = 0; q < QPW; ++q) {
                float sd = __builtin_fmaf(P.z, az[q], P.w);
                sd = __builtin_fmaf(P.y, ay[q], sd);
                sd = __builtin_fmaf(P.x, ax[q], sd);
                if (sd < best[q]) { best[q] = sd; idx[q] = j; }  // tie -> min idx
            }
        }
        #pragma unroll
        for (int off = 32; off; off >>= 1) {
            #pragma unroll
            for (int q = 0; q < QPW; ++q) {
                const float ov = __shfl_xor(best[q], off, 64);
                const int oi = __shfl_xor(idx[q], off, 64);
                if (ov < best[q] || (ov == best[q] && oi < idx[q])) {
                    best[q] = ov; idx[q] = oi;
                }
            }
        }

        // ---- per-wave Kabsch partials (lane 0) ----
        __syncthreads();
        if (lane == 0) {
            float Sx = 0, Sy = 0, Sz = 0, Tx = 0, Ty = 0, Tz = 0;
            float m0 = 0, m1 = 0, m2 = 0, m3 = 0, m4 = 0, m5 = 0, m6 = 0, m7 = 0, m8 = 0;
            #pragma unroll
            for (int q = 0; q < QPW; ++q) {
                const float4 M = sp2[idx[q]];
                Sx += qx[q]; Sy += qy[q]; Sz += qz[q];
                Tx += M.x;  Ty += M.y;  Tz += M.z;
                m0 += qx[q] * M.x; m1 += qx[q] * M.y; m2 += qx[q] * M.z;
                m3 += qy[q] * M.x; m4 += qy[q] * M.y; m5 += qy[q] * M.z;
                m6 += qz[q] * M.x; m7 += qz[q] * M.y; m8 += qz[q] * M.z;
            }
            float* r = wred[wave];
            r[0] = Sx; r[1] = Sy; r[2] = Sz;
            r[3] = Tx; r[4] = Ty; r[5] = Tz;
            r[6] = m0; r[7] = m1; r[8] = m2;
            r[9] = m3; r[10] = m4; r[11] = m5;
            r[12] = m6; r[13] = m7; r[14] = m8;
            r[15] = 0.0f;
        }
        __syncthreads();
        // block sums -> fixed-point int64 (exact, deterministic)
        if (tid < 15) {
            float bs = 0.0f;
            #pragma unroll
            for (int w2 = 0; w2 < NWAVE; ++w2) bs += wred[w2][tid];
            sred[tid] = llrint((double)bs * FP_SCALE);
        }
        __syncthreads();
        if (tid == 0) {
            long long cs1 = 0, cs2 = 0;
            #pragma unroll
            for (int k = 0; k < 15; ++k) {
                cs1 += sred[k];
                cs2 += (long long)(k + 1) * sred[k];
            }
            sred[15] = cs1; sred[16] = cs2; sred[17] = 1;
        }
        __syncthreads();

        // ---- publish own row: 18 write-through stores, zero contention ----
        unsigned long long* srows = rows + (size_t)s * NBLK * RSLOT;
        if (tid < RSLOT) ast64(&srows[(size_t)bid * RSLOT + tid], (unsigned long long)sred[tid]);

        // ---- read all 256 rows (one per thread), verify by checksum ----
        long long rv[15];
        bool valid = false;
        for (;;) {
            if (!valid) {
                const unsigned long long* r = srows + (size_t)tid * RSLOT;
                long long t[RSLOT];
                #pragma unroll
                for (int i = 0; i < RSLOT; ++i) t[i] = (long long)ald64(&r[i]);
                long long c1 = 0, c2 = 0;
                #pragma unroll
                for (int k = 0; k < 15; ++k) {
                    c1 += t[k];
                    c2 += (long long)(k + 1) * t[k];
                }
                if (t[17] == 1 && c1 == t[15] && c2 == t[16]) {
                    #pragma unroll
                    for (int k = 0; k < 15; ++k) rv[k] = t[k];
                    valid = true;
                }
            }
            if (__syncthreads_count(valid ? 0 : 1) == 0) break;
        }

        // ---- block-local exact reduction (identical in every block) ----
        #pragma unroll
        for (int i = 0; i < 15; ++i) {
            long long v = rv[i];
            #pragma unroll
            for (int off = 32; off; off >>= 1) v += __shfl_xor(v, off, 64);
            if (lane == 0) lred[wave][i] = v;
        }
        __syncthreads();
        if (tid < 15) {
            long long sm = 0;
            #pragma unroll
            for (int w2 = 0; w2 < NWAVE; ++w2) sm += lred[w2][tid];
            sH[tid] = (float)((double)sm * FP_INV);
        }
        __syncthreads();

        // ---- every block solves Horn redundantly (identical inputs) ----
        const float S1x = sH[0], S1y = sH[1], S1z = sH[2];
        const float S2x = sH[3], S2y = sH[4], S2z = sH[5];
        const float Mxx = sH[6], Mxy = sH[7], Mxz = sH[8];
        const float Myx = sH[9], Myy = sH[10], Myz = sH[11];
        const float Mzx = sH[12], Mzy = sH[13], Mzz = sH[14];

        const float invN = 1.0f / (float)N_PTS;
        const float c1x = S1x * invN, c1y = S1y * invN, c1z = S1z * invN;
        const float c2x = S2x * invN, c2y = S2y * invN, c2z = S2z * invN;

        const float Sxx = Mxx - S1x * S2x * invN;
        const float Sxy = Mxy - S1x * S2y * invN;
        const float Sxz = Mxz - S1x * S2z * invN;
        const float Syx = Myx - S1y * S2x * invN;
        const float Syy = Myy - S1y * S2y * invN;
        const float Syz = Myz - S1y * S2z * invN;
        const float Szx = Mzx - S1z * S2x * invN;
        const float Szy = Mzy - S1z * S2y * invN;
        const float Szz = Mzz - S1z * S2z * invN;

        const float N00 = Sxx + Syy + Szz;
        const float N01 = Syz - Szy;
        const float N02 = Szx - Sxz;
        const float N03 = Sxy - Syx;
        const float N11 = Sxx - Syy - Szz;
        const float N12 = Sxy + Syx;
        const float N13 = Szx + Sxz;
        const float N22 = -Sxx + Syy - Szz;
        const float N23 = Syz + Szy;
        const float N33 = -Sxx - Syy + Szz;

        const float fro = sqrtf(N00 * N00 + N11 * N11 + N22 * N22 + N33 * N33 +
                                2.0f * (N01 * N01 + N02 * N02 + N03 * N03 +
                                        N12 * N12 + N13 * N13 + N23 * N23));
        const float sg = fro + 1e-20f;

        float w = 1.0f, x = 0.0f, y = 0.0f, z = 0.0f;
        for (int it = 0; it < POWER_ITERS; ++it) {
            const float r0 = N00 * w + N01 * x + N02 * y + N03 * z + sg * w;
            const float r1 = N01 * w + N11 * x + N12 * y + N13 * z + sg * x;
            const float r2 = N02 * w + N12 * x + N22 * y + N23 * z + sg * y;
            const float r3 = N03 * w + N13 * x + N23 * y + N33 * z + sg * z;
            const float inv = rsqrtf(r0 * r0 + r1 * r1 + r2 * r2 + r3 * r3 + 1e-30f);
            w = r0 * inv; x = r1 * inv; y = r2 * inv; z = r3 * inv;
        }

        const float xx = x * x, yy = y * y, zz = z * z;
        const float xy = x * y, xz = x * z, yz = y * z;
        const float wx = w * x, wy = w * y, wz = w * z;
        const float R00 = 1.0f - 2.0f * (yy + zz), R01 = 2.0f * (xy - wz), R02 = 2.0f * (xz + wy);
        const float R10 = 2.0f * (xy + wz), R11 = 1.0f - 2.0f * (xx + zz), R12 = 2.0f * (yz - wx);
        const float R20 = 2.0f * (xz - wy), R21 = 2.0f * (yz + wx), R22 = 1.0f - 2.0f * (xx + yy);

        const float tx = c2x - (R00 * c1x + R01 * c1y + R02 * c1z);
        const float ty = c2y - (R10 * c1x + R11 * c1y + R12 * c1z);
        const float tz = c2z - (R20 * c1x + R21 * c1y + R22 * c1z);

        // transform owned queries
        #pragma unroll
        for (int q = 0; q < QPW; ++q) {
            const float nx0 = R00 * qx[q] + R01 * qy[q] + R02 * qz[q] + tx;
            const float ny0 = R10 * qx[q] + R11 * qy[q] + R12 * qz[q] + ty;
            const float nz0 = R20 * qx[q] + R21 * qy[q] + R22 * qz[q] + tz;
            qx[q] = nx0; qy[q] = ny0; qz[q] = nz0;
        }

        // compose totals: q_tot = q_step (*) q_tot ; t_tot = R_step t_tot + t_step
        {
            const float nw = w * cqw - x * cqx - y * cqy - z * cqz;
            const float nx = w * cqx + x * cqw + y * cqz - z * cqy;
            const float ny = w * cqy - x * cqz + y * cqw + z * cqx;
            const float nz = w * cqz + x * cqy - y * cqx + z * cqw;
            cqw = nw; cqx = nx; cqy = ny; cqz = nz;
            const float ntx = R00 * ctx + R01 * cty + R02 * ctz + tx;
            const float nty = R10 * ctx + R11 * cty + R12 * ctz + ty;
            const float ntz = R20 * ctx + R21 * cty + R22 * ctz + tz;
            ctx = ntx; cty = nty; ctz = ntz;
        }
    }

    // final Kabsch(p1, pc) == composed transform (exact; H = C*Rc^T, C SPD)
    if (bid == 0 && tid == 0) {
        const float fxx = cqx * cqx, fyy = cqy * cqy, fzz = cqz * cqz;
        const float fxy = cqx * cqy, fxz = cqx * cqz, fyz = cqy * cqz;
        const float fwx = cqw * cqx, fwy = cqw * cqy, fwz = cqw * cqz;
        out[0]  = 1.0f - 2.0f * (fyy + fzz);
        out[1]  = 2.0f * (fxy - fwz);
        out[2]  = 2.0f * (fxz + fwy);
        out[3]  = ctx;
        out[4]  = 2.0f * (fxy + fwz);
        out[5]  = 1.0f - 2.0f * (fxx + fzz);
        out[6]  = 2.0f * (fyz - fwx);
        out[7]  = cty;
        out[8]  = 2.0f * (fxz - fwy);
        out[9]  = 2.0f * (fyz + fwx);
        out[10] = 1.0f - 2.0f * (fxx + fyy);
        out[11] = ctz;
    }
}

extern "C" void kernel_launch(void* const* d_in, const int* in_sizes, int n_in,
                              void* d_out, int out_size, void* d_ws, size_t ws_size,
                              hipStream_t stream) {
    const float* p1 = (const float*)d_in[0];
    const float* p2 = (const float*)d_in[1];
    float* out = (float*)d_out;
    unsigned long long* rows = (unsigned long long*)d_ws;  // 10*256*18*8 = 360 KB

    void* args[] = {(void*)&p1, (void*)&p2, (void*)&rows, (void*)&out};
    hipLaunchCooperativeKernel((const void*)icp_pk, dim3(NBLK), dim3(BS), args, 0, stream);
}

// Round 8
// 200.697 us; speedup vs baseline: 1.3301x; 1.3301x over previous
//
#include <hip/hip_runtime.h>

#define N_PTS 4096
#define ICP_STEPS 10
#define NBLK 256          // 1 block/CU (cooperative launch guarantees co-residency)
#define BS 256            // 4 waves/block; 4 queries per wave -> 16 queries/block
#define NWAVE (BS / 64)
#define QPW 4
#define POWER_ITERS 16
#define NCOL 8            // accumulator columns; block bid adds into column bid&7
#define CSTRIDE 32        // u64 stride per column (256 B; spreads channels)
#define FP_SCALE 16777216.0   // 2^24 fixed point
#define FP_INV   (1.0 / 16777216.0)

// acc: [ICP_STEPS][NCOL][CSTRIDE] u64, zeroed by hipMemsetAsync pre-launch.
// Column layout: slots 0-14 data, 15 cs1, 16 cs2, 17 count.
#define ACC_U64S (ICP_STEPS * NCOL * CSTRIDE)   // 2560 u64 = 20480 B

__device__ __forceinline__ unsigned long long au64_add(unsigned long long* p,
                                                       unsigned long long v) {
    return __hip_atomic_fetch_add(p, v, __ATOMIC_RELAXED, __HIP_MEMORY_SCOPE_AGENT);
}
__device__ __forceinline__ unsigned long long ald64(const unsigned long long* p) {
    return __hip_atomic_load(p, __ATOMIC_RELAXED, __HIP_MEMORY_SCOPE_AGENT);
}

__global__ __launch_bounds__(BS, 1) void icp_pk(const float* __restrict__ p1,
                                                const float* __restrict__ p2,
                                                unsigned long long* __restrict__ acc,
                                                float* __restrict__ out) {
    __shared__ __align__(16) float4 sp2[N_PTS];   // 64 KB {x,y,z,|p|^2}
    __shared__ float wred[NWAVE][16];
    __shared__ long long sred[18];
    __shared__ long long cdat[NCOL][15];
    __shared__ int okf[NCOL];
    __shared__ float sH[16];

    const int tid = threadIdx.x;
    const int bid = blockIdx.x;
    const int wave = tid >> 6;
    const int lane = tid & 63;
    // read-verify mapping: each 32-lane half-wave owns one column
    const int colw = (wave << 1) | (lane >> 5);   // 0..7
    const int slot = lane & 31;                   // 0..31 (18 used)
    const int hbase = lane & 32;                  // half-wave base for __shfl

    // ---- stage p2 -> LDS once ----
    for (int p = tid; p < N_PTS; p += BS) {
        const float x = p2[3 * p + 0];
        const float y = p2[3 * p + 1];
        const float z = p2[3 * p + 2];
        sp2[p] = make_float4(x, y, z, x * x + y * y + z * z);
    }

    // ---- owned queries: 16/block, 4/wave (all lanes track the same 4) ----
    const int qb = bid * 16 + wave * QPW;
    float qx[QPW], qy[QPW], qz[QPW];
    #pragma unroll
    for (int j = 0; j < QPW; ++j) {
        qx[j] = p1[3 * (qb + j) + 0];
        qy[j] = p1[3 * (qb + j) + 1];
        qz[j] = p1[3 * (qb + j) + 2];
    }

    // composed transform (identical in all blocks; bid0 writes out)
    float cqw = 1.0f, cqx = 0.0f, cqy = 0.0f, cqz = 0.0f;
    float ctx = 0.0f, cty = 0.0f, ctz = 0.0f;

    __syncthreads();

    for (int s = 0; s < ICP_STEPS; ++s) {
        // ---- 1-NN for 4 queries: argmin_j (|p_j|^2 - 2 q.p_j) ----
        float ax[QPW], ay[QPW], az[QPW], best[QPW];
        int idx[QPW];
        #pragma unroll
        for (int j = 0; j < QPW; ++j) {
            ax[j] = -2.0f * qx[j]; ay[j] = -2.0f * qy[j]; az[j] = -2.0f * qz[j];
            best[j] = 3.4e38f; idx[j] = 0;
        }
        #pragma unroll 8
        for (int k = 0; k < N_PTS / 64; ++k) {
            const int j = lane + (k << 6);
            const float4 P = sp2[j];
            #pragma unroll
            for (int q = 0; q < QPW; ++q) {
                float sd = __builtin_fmaf(P.z, az[q], P.w);
                sd = __builtin_fmaf(P.y, ay[q], sd);
                sd = __builtin_fmaf(P.x, ax[q], sd);
                if (sd < best[q]) { best[q] = sd; idx[q] = j; }  // tie -> min idx
            }
        }
        #pragma unroll
        for (int off = 32; off; off >>= 1) {
            #pragma unroll
            for (int q = 0; q < QPW; ++q) {
                const float ov = __shfl_xor(best[q], off, 64);
                const int oi = __shfl_xor(idx[q], off, 64);
                if (ov < best[q] || (ov == best[q] && oi < idx[q])) {
                    best[q] = ov; idx[q] = oi;
                }
            }
        }

        // ---- per-wave Kabsch partials (lane 0) ----
        __syncthreads();
        if (lane == 0) {
            float Sx = 0, Sy = 0, Sz = 0, Tx = 0, Ty = 0, Tz = 0;
            float m0 = 0, m1 = 0, m2 = 0, m3 = 0, m4 = 0, m5 = 0, m6 = 0, m7 = 0, m8 = 0;
            #pragma unroll
            for (int q = 0; q < QPW; ++q) {
                const float4 M = sp2[idx[q]];
                Sx += qx[q]; Sy += qy[q]; Sz += qz[q];
                Tx += M.x;  Ty += M.y;  Tz += M.z;
                m0 += qx[q] * M.x; m1 += qx[q] * M.y; m2 += qx[q] * M.z;
                m3 += qy[q] * M.x; m4 += qy[q] * M.y; m5 += qy[q] * M.z;
                m6 += qz[q] * M.x; m7 += qz[q] * M.y; m8 += qz[q] * M.z;
            }
            float* r = wred[wave];
            r[0] = Sx; r[1] = Sy; r[2] = Sz;
            r[3] = Tx; r[4] = Ty; r[5] = Tz;
            r[6] = m0; r[7] = m1; r[8] = m2;
            r[9] = m3; r[10] = m4; r[11] = m5;
            r[12] = m6; r[13] = m7; r[14] = m8;
            r[15] = 0.0f;
        }
        __syncthreads();
        // block sums -> fixed-point int64 (exact); checksums
        if (tid < 15) {
            float bs = 0.0f;
            #pragma unroll
            for (int w2 = 0; w2 < NWAVE; ++w2) bs += wred[w2][tid];
            sred[tid] = llrint((double)bs * FP_SCALE);
        }
        if (tid >= 64 && tid < 64 + NCOL) okf[tid - 64] = 0;   // init ok flags (wave 1)
        __syncthreads();
        if (tid == 0) {
            long long cs1 = 0, cs2 = 0;
            #pragma unroll
            for (int k = 0; k < 15; ++k) {
                cs1 += sred[k];
                cs2 += (long long)(k + 1) * sred[k];
            }
            sred[15] = cs1; sred[16] = cs2; sred[17] = 1;
        }
        __syncthreads();

        // ---- write volley: 18 RMW adds into own column (32 writers/address) ----
        unsigned long long* sacc = acc + (size_t)s * (NCOL * CSTRIDE);
        if (tid < 18)
            au64_add(&sacc[(size_t)(bid & (NCOL - 1)) * CSTRIDE + tid],
                     (unsigned long long)sred[tid]);

        // ---- poll: parallel loads of 8 columns, per-column checksum verify ----
        for (;;) {
            const bool colok = (okf[colw] != 0);
            long long v = 0;
            if (!colok && slot < 18)
                v = (long long)ald64(&sacc[(size_t)colw * CSTRIDE + slot]);
            if (!colok) {
                long long s1 = (slot < 15) ? v : 0;
                long long s2 = (slot < 15) ? (long long)(slot + 1) * v : 0;
                #pragma unroll
                for (int off = 16; off; off >>= 1) {      // stays within half-wave
                    s1 += __shfl_xor(s1, off, 64);
                    s2 += __shfl_xor(s2, off, 64);
                }
                const long long cs1 = __shfl(v, hbase + 15, 64);
                const long long cs2 = __shfl(v, hbase + 16, 64);
                const long long cnt = __shfl(v, hbase + 17, 64);
                if (cnt == (long long)(NBLK / NCOL) && s1 == cs1 && s2 == cs2) {
                    if (slot < 15) cdat[colw][slot] = v;
                    if (slot == 0) okf[colw] = 1;
                }
            }
            __syncthreads();
            int nok = 0;
            #pragma unroll
            for (int c = 0; c < NCOL; ++c) nok += okf[c];
            if (nok == NCOL) break;
            __syncthreads();   // protect okf re-read at loop top
        }

        // ---- exact global H (identical integers in every block) ----
        if (tid < 15) {
            long long sm = 0;
            #pragma unroll
            for (int c = 0; c < NCOL; ++c) sm += cdat[c][tid];
            sH[tid] = (float)((double)sm * FP_INV);
        }
        __syncthreads();

        // ---- redundant Horn solve ----
        const float S1x = sH[0], S1y = sH[1], S1z = sH[2];
        const float S2x = sH[3], S2y = sH[4], S2z = sH[5];
        const float Mxx = sH[6], Mxy = sH[7], Mxz = sH[8];
        const float Myx = sH[9], Myy = sH[10], Myz = sH[11];
        const float Mzx = sH[12], Mzy = sH[13], Mzz = sH[14];

        const float invN = 1.0f / (float)N_PTS;
        const float c1x = S1x * invN, c1y = S1y * invN, c1z = S1z * invN;
        const float c2x = S2x * invN, c2y = S2y * invN, c2z = S2z * invN;

        const float Sxx = Mxx - S1x * S2x * invN;
        const float Sxy = Mxy - S1x * S2y * invN;
        const float Sxz = Mxz - S1x * S2z * invN;
        const float Syx = Myx - S1y * S2x * invN;
        const float Syy = Myy - S1y * S2y * invN;
        const float Syz = Myz - S1y * S2z * invN;
        const float Szx = Mzx - S1z * S2x * invN;
        const float Szy = Mzy - S1z * S2y * invN;
        const float Szz = Mzz - S1z * S2z * invN;

        const float N00 = Sxx + Syy + Szz;
        const float N01 = Syz - Szy;
        const float N02 = Szx - Sxz;
        const float N03 = Sxy - Syx;
        const float N11 = Sxx - Syy - Szz;
        const float N12 = Sxy + Syx;
        const float N13 = Szx + Sxz;
        const float N22 = -Sxx + Syy - Szz;
        const float N23 = Syz + Szy;
        const float N33 = -Sxx - Syy + Szz;

        const float fro = sqrtf(N00 * N00 + N11 * N11 + N22 * N22 + N33 * N33 +
                                2.0f * (N01 * N01 + N02 * N02 + N03 * N03 +
                                        N12 * N12 + N13 * N13 + N23 * N23));
        const float sg = fro + 1e-20f;

        float w = 1.0f, x = 0.0f, y = 0.0f, z = 0.0f;
        for (int it = 0; it < POWER_ITERS; ++it) {
            const float r0 = N00 * w + N01 * x + N02 * y + N03 * z + sg * w;
            const float r1 = N01 * w + N11 * x + N12 * y + N13 * z + sg * x;
            const float r2 = N02 * w + N12 * x + N22 * y + N23 * z + sg * y;
            const float r3 = N03 * w + N13 * x + N23 * y + N33 * z + sg * z;
            const float inv = rsqrtf(r0 * r0 + r1 * r1 + r2 * r2 + r3 * r3 + 1e-30f);
            w = r0 * inv; x = r1 * inv; y = r2 * inv; z = r3 * inv;
        }

        const float xx = x * x, yy = y * y, zz = z * z;
        const float xy = x * y, xz = x * z, yz = y * z;
        const float wx = w * x, wy = w * y, wz = w * z;
        const float R00 = 1.0f - 2.0f * (yy + zz), R01 = 2.0f * (xy - wz), R02 = 2.0f * (xz + wy);
        const float R10 = 2.0f * (xy + wz), R11 = 1.0f - 2.0f * (xx + zz), R12 = 2.0f * (yz - wx);
        const float R20 = 2.0f * (xz - wy), R21 = 2.0f * (yz + wx), R22 = 1.0f - 2.0f * (xx + yy);

        const float tx = c2x - (R00 * c1x + R01 * c1y + R02 * c1z);
        const float ty = c2y - (R10 * c1x + R11 * c1y + R12 * c1z);
        const float tz = c2z - (R20 * c1x + R21 * c1y + R22 * c1z);

        // transform owned queries
        #pragma unroll
        for (int q = 0; q < QPW; ++q) {
            const float nx0 = R00 * qx[q] + R01 * qy[q] + R02 * qz[q] + tx;
            const float ny0 = R10 * qx[q] + R11 * qy[q] + R12 * qz[q] + ty;
            const float nz0 = R20 * qx[q] + R21 * qy[q] + R22 * qz[q] + tz;
            qx[q] = nx0; qy[q] = ny0; qz[q] = nz0;
        }

        // compose totals
        {
            const float nw = w * cqw - x * cqx - y * cqy - z * cqz;
            const float nx = w * cqx + x * cqw + y * cqz - z * cqy;
            const float ny = w * cqy - x * cqz + y * cqw + z * cqx;
            const float nz = w * cqz + x * cqy - y * cqx + z * cqw;
            cqw = nw; cqx = nx; cqy = ny; cqz = nz;
            const float ntx = R00 * ctx + R01 * cty + R02 * ctz + tx;
            const float nty = R10 * ctx + R11 * cty + R12 * ctz + ty;
            const float ntz = R20 * ctx + R21 * cty + R22 * ctz + tz;
            ctx = ntx; cty = nty; ctz = ntz;
        }
    }

    // final Kabsch(p1, pc) == composed transform (exact; H = C*Rc^T, C SPD)
    if (bid == 0 && tid == 0) {
        const float fxx = cqx * cqx, fyy = cqy * cqy, fzz = cqz * cqz;
        const float fxy = cqx * cqy, fxz = cqx * cqz, fyz = cqy * cqz;
        const float fwx = cqw * cqx, fwy = cqw * cqy, fwz = cqw * cqz;
        out[0]  = 1.0f - 2.0f * (fyy + fzz);
        out[1]  = 2.0f * (fxy - fwz);
        out[2]  = 2.0f * (fxz + fwy);
        out[3]  = ctx;
        out[4]  = 2.0f * (fxy + fwz);
        out[5]  = 1.0f - 2.0f * (fxx + fzz);
        out[6]  = 2.0f * (fyz - fwx);
        out[7]  = cty;
        out[8]  = 2.0f * (fxz - fwy);
        out[9]  = 2.0f * (fyz + fwx);
        out[10] = 1.0f - 2.0f * (fxx + fyy);
        out[11] = ctz;
    }
}

extern "C" void kernel_launch(void* const* d_in, const int* in_sizes, int n_in,
                              void* d_out, int out_size, void* d_ws, size_t ws_size,
                              hipStream_t stream) {
    const float* p1 = (const float*)d_in[0];
    const float* p2 = (const float*)d_in[1];
    float* out = (float*)d_out;
    unsigned long long* acc = (unsigned long long*)d_ws;

    hipMemsetAsync(acc, 0, ACC_U64S * sizeof(unsigned long long), stream);

    void* args[] = {(void*)&p1, (void*)&p2, (void*)&acc, (void*)&out};
    hipLaunchCooperativeKernel((const void*)icp_pk, dim3(NBLK), dim3(BS), args, 0, stream);
}